// Round 3
// baseline (985.206 us; speedup 1.0000x reference)
//
#include <hip/hip_runtime.h>

#define N_VOX 200000
#define EPS_BN 1e-5f

typedef __bf16 bf16x8 __attribute__((ext_vector_type(8)));
typedef float f32x4 __attribute__((ext_vector_type(4)));

__device__ __forceinline__ unsigned short f2bf(float f) {
    union { float f; unsigned int i; } x; x.f = f;
    unsigned int r = x.i + 0x7fffu + ((x.i >> 16) & 1u);  // RNE
    return (unsigned short)(r >> 16);
}

// ---------------- inverse kernel-map ----------------
__global__ void fill_inv_kernel(int* __restrict__ inv) {
    const int tot = 27 * N_VOX;
    for (int i = blockIdx.x * 256 + threadIdx.x; i < tot; i += gridDim.x * 256)
        inv[i] = N_VOX;
}

__global__ void build_inv_kernel(const int* __restrict__ sidx, const int* __restrict__ gidx,
                                 int* __restrict__ inv) {
    int k = blockIdx.y;
    int p = blockIdx.x * 256 + threadIdx.x;
    if (p < N_VOX) {
        int s = sidx[k * N_VOX + p];
        if (s < N_VOX) inv[k * N_VOX + s] = gidx[k * N_VOX + p];  // unique s per k -> no race
    }
}

// ---------------- weight transpose + fp32->bf16: w[k][a][b] -> wt[k][b][a] ----------------
__global__ void tr_w1_kernel(const float* __restrict__ w, unsigned short* __restrict__ wt) {
    int k = blockIdx.y; int idx = blockIdx.x * 256 + threadIdx.x;  // < 8192
    int a = idx >> 7, b = idx & 127;
    wt[k * 8192 + b * 64 + a] = f2bf(w[k * 8192 + idx]);
}
__global__ void tr_w2_kernel(const float* __restrict__ w, unsigned short* __restrict__ wt) {
    int k = blockIdx.y; int idx = blockIdx.x * 256 + threadIdx.x;  // < 16384
    int a = idx >> 7, b = idx & 127;
    wt[k * 16384 + b * 128 + a] = f2bf(w[k * 16384 + idx]);
}
__global__ void tr_wn_kernel(const float* __restrict__ w, unsigned short* __restrict__ wt) {
    int idx = blockIdx.x * 256 + threadIdx.x;  // < 8192
    int a = idx >> 7, b = idx & 127;
    wt[b * 64 + a] = f2bf(w[idx]);
}

// ---------------- BN stats ----------------
__global__ void stats1_kernel(const float* __restrict__ feats,
                              float* __restrict__ sum, float* __restrict__ sq) {
    int t = threadIdx.x; int c = t & 63; int rg = t >> 6;  // 4 row-groups
    float s = 0.f, q = 0.f;
    for (int row = blockIdx.x * 4 + rg; row < N_VOX; row += gridDim.x * 4) {
        float x = feats[(size_t)row * 64 + c];
        s += x; q += x * x;
    }
    __shared__ float red[8][64];
    red[rg][c] = s; red[4 + rg][c] = q;
    __syncthreads();
    if (t < 64) atomicAdd(&sum[t], red[0][t] + red[1][t] + red[2][t] + red[3][t]);
    else if (t < 128) { int cc = t - 64; atomicAdd(&sq[cc], red[4][cc] + red[5][cc] + red[6][cc] + red[7][cc]); }
}

__global__ void stats2_kernel(const unsigned short* __restrict__ h1b,
                              float* __restrict__ sum, float* __restrict__ sq) {
    int t = threadIdx.x; int c = t & 127; int rg = t >> 7;  // 2 row-groups
    float s = 0.f, q = 0.f;
    for (int row = blockIdx.x * 2 + rg; row < N_VOX; row += gridDim.x * 2) {
        union { float f; unsigned int i; } x;
        x.i = ((unsigned int)h1b[(size_t)row * 128 + c]) << 16;
        s += x.f; q += x.f * x.f;
    }
    __shared__ float red[4][128];
    red[rg][c] = s; red[2 + rg][c] = q;
    __syncthreads();
    if (t < 128) atomicAdd(&sum[t], red[0][t] + red[1][t]);
    else { int cc = t - 128; atomicAdd(&sq[cc], red[2][cc] + red[3][cc]); }
}

// ---------------- conv1: h1[i] = sum_k BN1(feats[inv[k][i]]) @ w1[k]  (64->128, bf16 out) ----
// block = 256 thr = 4 waves; block tile 64 voxels x 128 out-ch; wave = 32 vox x 64 ch
__global__ __launch_bounds__(256) void conv1_kernel(
    const float* __restrict__ feats, const unsigned short* __restrict__ w1t,
    const int* __restrict__ inv, const float* __restrict__ gamma,
    const float* __restrict__ beta, const float* __restrict__ ssum,
    const float* __restrict__ ssq, unsigned short* __restrict__ h1b) {
    __shared__ __align__(16) unsigned short sA[64][72];   // 64 vox x 64 ch (+8 pad, 144B rows)
    __shared__ __align__(16) unsigned short sB[128][72];  // 128 out-ch x 64 in-ch (+8 pad)
    __shared__ float sScale[64], sShift[64];

    const int t = threadIdx.x;
    if (t < 64) {
        float mean = ssum[t] * (1.0f / N_VOX);
        float var  = ssq[t] * (1.0f / N_VOX) - mean * mean;
        float sc   = gamma[t] * rsqrtf(var + EPS_BN);
        sScale[t] = sc;
        sShift[t] = beta[t] - mean * sc;
    }
    __syncthreads();

    const int v0 = blockIdx.x * 64;
    const int lane = t & 63, wv = t >> 6;
    const int mh = wv & 1, nh = wv >> 1;
    const int l16 = lane & 15, quad = lane >> 4;
    const int a_vl = t >> 2, a_cq = (t & 3) * 16;   // A-stage: 16 ch per thread
    const int b_row = t >> 1, b_part = (t & 1) * 32; // B-stage: 32 ch per thread

    f32x4 acc[2][4] = {};

    for (int k = 0; k < 27; k++) {
        // ---- stage A (gather fp32 + BN1 -> bf16) ----
        {
            int g = inv[k * N_VOX + v0 + a_vl];
            union { uint4 q[2]; unsigned short u[16]; } ov;
            if (g < N_VOX) {
                const float4* src = (const float4*)(feats + (size_t)g * 64 + a_cq);
                float fv[16];
#pragma unroll
                for (int j = 0; j < 4; j++) {
                    float4 f = src[j];
                    fv[j * 4 + 0] = f.x; fv[j * 4 + 1] = f.y;
                    fv[j * 4 + 2] = f.z; fv[j * 4 + 3] = f.w;
                }
#pragma unroll
                for (int j = 0; j < 16; j++)
                    ov.u[j] = f2bf(fv[j] * sScale[a_cq + j] + sShift[a_cq + j]);
            } else {
                ov.q[0] = make_uint4(0, 0, 0, 0); ov.q[1] = make_uint4(0, 0, 0, 0);
            }
            uint4* dst = (uint4*)&sA[a_vl][a_cq];
            dst[0] = ov.q[0]; dst[1] = ov.q[1];
        }
        // ---- stage B (w1t slice, coalesced copy) ----
        {
            const uint4* src = (const uint4*)(w1t + k * 8192 + b_row * 64 + b_part);
            uint4* dst = (uint4*)&sB[b_row][b_part];
#pragma unroll
            for (int j = 0; j < 4; j++) dst[j] = src[j];
        }
        __syncthreads();
#pragma unroll
        for (int ks = 0; ks < 2; ks++) {
            const int kc = ks * 32 + quad * 8;
            bf16x8 a0 = *(const bf16x8*)&sA[mh * 32 + l16][kc];
            bf16x8 a1 = *(const bf16x8*)&sA[mh * 32 + 16 + l16][kc];
#pragma unroll
            for (int ni = 0; ni < 4; ni++) {
                bf16x8 bfr = *(const bf16x8*)&sB[nh * 64 + ni * 16 + l16][kc];
                acc[0][ni] = __builtin_amdgcn_mfma_f32_16x16x32_bf16(a0, bfr, acc[0][ni], 0, 0, 0);
                acc[1][ni] = __builtin_amdgcn_mfma_f32_16x16x32_bf16(a1, bfr, acc[1][ni], 0, 0, 0);
            }
        }
        __syncthreads();
    }
#pragma unroll
    for (int mi = 0; mi < 2; mi++)
#pragma unroll
        for (int ni = 0; ni < 4; ni++)
#pragma unroll
            for (int r = 0; r < 4; r++) {
                int v  = v0 + mh * 32 + mi * 16 + quad * 4 + r;
                int ch = nh * 64 + ni * 16 + l16;
                h1b[(size_t)v * 128 + ch] = f2bf(acc[mi][ni][r]);
            }
}

// ---------------- conv2 + skip: out[i] = sum_k BN2(h1[inv[k][i]]) @ w2[k] + feats[i] @ w_nin ----
__global__ __launch_bounds__(256) void conv2_kernel(
    const unsigned short* __restrict__ h1b, const float* __restrict__ feats,
    const unsigned short* __restrict__ w2t, const unsigned short* __restrict__ w_nint,
    const int* __restrict__ inv, const float* __restrict__ gamma,
    const float* __restrict__ beta, const float* __restrict__ ssum,
    const float* __restrict__ ssq, float* __restrict__ out) {
    __shared__ __align__(16) unsigned short sA[64][136];   // 64 vox x 128 ch (+8 pad, 272B rows)
    __shared__ __align__(16) unsigned short sB[128][136];  // 128 out-ch x 128 in-ch (+8 pad)
    __shared__ float sScale[128], sShift[128];

    const int t = threadIdx.x;
    if (t < 128) {
        float mean = ssum[t] * (1.0f / N_VOX);
        float var  = ssq[t] * (1.0f / N_VOX) - mean * mean;
        float sc   = gamma[t] * rsqrtf(var + EPS_BN);
        sScale[t] = sc;
        sShift[t] = beta[t] - mean * sc;
    }
    __syncthreads();

    const int v0 = blockIdx.x * 64;
    const int lane = t & 63, wv = t >> 6;
    const int mh = wv & 1, nh = wv >> 1;
    const int l16 = lane & 15, quad = lane >> 4;
    const int a_vl = t >> 2, a_cq = (t & 3) * 32;    // A-stage: 32 ch per thread
    const int b_row = t >> 1, b_part = (t & 1) * 64; // B-stage: 64 ch per thread

    f32x4 acc[2][4] = {};

    for (int k = 0; k < 28; k++) {  // k==27 is the fused 1x1 skip (identity gather, no BN)
        union { uint4 q[4]; unsigned short u[32]; } ov;
        if (k < 27) {
            int g = inv[k * N_VOX + v0 + a_vl];
            if (g < N_VOX) {
                const uint4* src = (const uint4*)(h1b + (size_t)g * 128 + a_cq);
                union { uint4 q[4]; unsigned short u[32]; } iv;
#pragma unroll
                for (int j = 0; j < 4; j++) iv.q[j] = src[j];
#pragma unroll
                for (int j = 0; j < 32; j++) {
                    int c = a_cq + j;
                    union { float f; unsigned int i; } x;
                    x.i = ((unsigned int)iv.u[j]) << 16;
                    ov.u[j] = f2bf(x.f * sScale[c] + sShift[c]);
                }
            } else {
#pragma unroll
                for (int j = 0; j < 4; j++) ov.q[j] = make_uint4(0, 0, 0, 0);
            }
            const uint4* src = (const uint4*)(w2t + k * 16384 + b_row * 128 + b_part);
            uint4* dst = (uint4*)&sB[b_row][b_part];
#pragma unroll
            for (int j = 0; j < 8; j++) dst[j] = src[j];
        } else {
            if (a_cq < 64) {  // raw fp32 feats -> bf16 (no BN), channels 64..127 zero-padded
                const float4* src = (const float4*)(feats + (size_t)(v0 + a_vl) * 64 + a_cq);
#pragma unroll
                for (int j = 0; j < 8; j++) {
                    float4 f = src[j];
                    ov.u[j * 4 + 0] = f2bf(f.x); ov.u[j * 4 + 1] = f2bf(f.y);
                    ov.u[j * 4 + 2] = f2bf(f.z); ov.u[j * 4 + 3] = f2bf(f.w);
                }
            } else {
#pragma unroll
                for (int j = 0; j < 4; j++) ov.q[j] = make_uint4(0, 0, 0, 0);
            }
            uint4* dst = (uint4*)&sB[b_row][b_part];
            if (b_part == 0) {
                const uint4* src = (const uint4*)(w_nint + b_row * 64);
#pragma unroll
                for (int j = 0; j < 8; j++) dst[j] = src[j];
            } else {
#pragma unroll
                for (int j = 0; j < 8; j++) dst[j] = make_uint4(0, 0, 0, 0);
            }
        }
        {
            uint4* dst = (uint4*)&sA[a_vl][a_cq];
#pragma unroll
            for (int j = 0; j < 4; j++) dst[j] = ov.q[j];
        }
        __syncthreads();
#pragma unroll
        for (int ks = 0; ks < 4; ks++) {
            const int kc = ks * 32 + quad * 8;
            bf16x8 a0 = *(const bf16x8*)&sA[mh * 32 + l16][kc];
            bf16x8 a1 = *(const bf16x8*)&sA[mh * 32 + 16 + l16][kc];
#pragma unroll
            for (int ni = 0; ni < 4; ni++) {
                bf16x8 bfr = *(const bf16x8*)&sB[nh * 64 + ni * 16 + l16][kc];
                acc[0][ni] = __builtin_amdgcn_mfma_f32_16x16x32_bf16(a0, bfr, acc[0][ni], 0, 0, 0);
                acc[1][ni] = __builtin_amdgcn_mfma_f32_16x16x32_bf16(a1, bfr, acc[1][ni], 0, 0, 0);
            }
        }
        __syncthreads();
    }
#pragma unroll
    for (int mi = 0; mi < 2; mi++)
#pragma unroll
        for (int ni = 0; ni < 4; ni++)
#pragma unroll
            for (int r = 0; r < 4; r++) {
                int v  = v0 + mh * 32 + mi * 16 + quad * 4 + r;
                int ch = nh * 64 + ni * 16 + l16;
                out[(size_t)v * 128 + ch] = acc[mi][ni][r];
            }
}

extern "C" void kernel_launch(void* const* d_in, const int* in_sizes, int n_in,
                              void* d_out, int out_size, void* d_ws, size_t ws_size,
                              hipStream_t stream) {
    const float* feats = (const float*)d_in[0];
    const float* w1    = (const float*)d_in[1];
    const float* w2    = (const float*)d_in[2];
    const float* w_nin = (const float*)d_in[3];
    const float* g1    = (const float*)d_in[4];
    const float* b1    = (const float*)d_in[5];
    const float* g2    = (const float*)d_in[6];
    const float* b2    = (const float*)d_in[7];
    const int* gidx = (const int*)d_in[8];
    const int* sidx = (const int*)d_in[9];
    float* out = (float*)d_out;

    // workspace layout (total ~74.2 MB)
    char* ws = (char*)d_ws;
    int* inv              = (int*)(ws);                         // 27*200000*4  = 21,600,000
    unsigned short* h1b   = (unsigned short*)(ws + 21600000);   // 200000*128*2 = 51,200,000
    unsigned short* w1t   = (unsigned short*)(ws + 72800000);   // 442,368
    unsigned short* w2t   = (unsigned short*)(ws + 73242368);   // 884,736
    unsigned short* w_nint= (unsigned short*)(ws + 74127104);   // 16,384
    float* stats          = (float*)(ws + 74143488);            // 384 floats
    float* s1sum = stats, *s1sq = stats + 64, *s2sum = stats + 128, *s2sq = stats + 256;

    hipMemsetAsync(stats, 0, 384 * sizeof(float), stream);
    fill_inv_kernel<<<2048, 256, 0, stream>>>(inv);
    build_inv_kernel<<<dim3(782, 27), 256, 0, stream>>>(sidx, gidx, inv);
    tr_w1_kernel<<<dim3(32, 27), 256, 0, stream>>>(w1, w1t);
    tr_w2_kernel<<<dim3(64, 27), 256, 0, stream>>>(w2, w2t);
    tr_wn_kernel<<<32, 256, 0, stream>>>(w_nin, w_nint);
    stats1_kernel<<<512, 256, 0, stream>>>(feats, s1sum, s1sq);
    conv1_kernel<<<3125, 256, 0, stream>>>(feats, w1t, inv, g1, b1, s1sum, s1sq, h1b);
    stats2_kernel<<<512, 256, 0, stream>>>(h1b, s2sum, s2sq);
    conv2_kernel<<<3125, 256, 0, stream>>>(h1b, feats, w2t, w_nint, inv, g2, b2, s2sum, s2sq, out);
}

// Round 4
// 859.963 us; speedup vs baseline: 1.1456x; 1.1456x over previous
//
#include <hip/hip_runtime.h>

#define N_VOX 200000
#define NPAD_INV (27 * N_VOX + 128)
#define EPS_BN 1e-5f

typedef __bf16 bf16x8 __attribute__((ext_vector_type(8)));
typedef float f32x4 __attribute__((ext_vector_type(4)));

__device__ __forceinline__ float bf2f(unsigned short u) {
    union { float f; unsigned int i; } x; x.i = ((unsigned int)u) << 16; return x.f;
}
__device__ __forceinline__ unsigned short f2bf(float f) {
    union { float f; unsigned int i; } x; x.f = f;
    unsigned int r = x.i + 0x7fffu + ((x.i >> 16) & 1u);  // RNE
    return (unsigned short)(r >> 16);
}

// async 16B/lane global->LDS; LDS dest = wave-uniform base + lane*16
#define ASYNC16(gsrc, ldst)                                                             \
    __builtin_amdgcn_global_load_lds(                                                   \
        (const __attribute__((address_space(1))) void*)(gsrc),                          \
        (__attribute__((address_space(3))) void*)(ldst), 16, 0, 0)

// ---------------- inverse kernel-map ----------------
__global__ void fill_inv_kernel(int* __restrict__ inv) {
    for (int i = blockIdx.x * 256 + threadIdx.x; i < NPAD_INV; i += gridDim.x * 256)
        inv[i] = N_VOX;
}

__global__ void build_inv_kernel(const int* __restrict__ sidx, const int* __restrict__ gidx,
                                 int* __restrict__ inv) {
    int k = blockIdx.y;
    int p = blockIdx.x * 256 + threadIdx.x;
    if (p < N_VOX) {
        int s = sidx[k * N_VOX + p];
        if (s < N_VOX) inv[k * N_VOX + s] = gidx[k * N_VOX + p];  // unique s per k -> no race
    }
}

// ---------------- weight transpose + fp32->bf16: w[k][a][b] -> wt[k][b][a] ----------------
__global__ void tr_w1_kernel(const float* __restrict__ w, unsigned short* __restrict__ wt) {
    int k = blockIdx.y; int idx = blockIdx.x * 256 + threadIdx.x;  // < 8192
    int a = idx >> 7, b = idx & 127;
    wt[k * 8192 + b * 64 + a] = f2bf(w[k * 8192 + idx]);
}
__global__ void tr_w2_kernel(const float* __restrict__ w, unsigned short* __restrict__ wt) {
    int k = blockIdx.y; int idx = blockIdx.x * 256 + threadIdx.x;  // < 16384
    int a = idx >> 7, b = idx & 127;
    wt[k * 16384 + b * 128 + a] = f2bf(w[k * 16384 + idx]);
}
__global__ void tr_wn_kernel(const float* __restrict__ w, unsigned short* __restrict__ wt) {
    int idx = blockIdx.x * 256 + threadIdx.x;  // < 8192
    int a = idx >> 7, b = idx & 127;
    wt[b * 64 + a] = f2bf(w[idx]);
}

// ---------------- BN stats ----------------
__global__ void stats1_kernel(const float* __restrict__ feats,
                              float* __restrict__ sum, float* __restrict__ sq) {
    int t = threadIdx.x; int c = t & 63; int rg = t >> 6;
    float s = 0.f, q = 0.f;
    for (int row = blockIdx.x * 4 + rg; row < N_VOX; row += gridDim.x * 4) {
        float x = feats[(size_t)row * 64 + c];
        s += x; q += x * x;
    }
    __shared__ float red[8][64];
    red[rg][c] = s; red[4 + rg][c] = q;
    __syncthreads();
    if (t < 64) atomicAdd(&sum[t], red[0][t] + red[1][t] + red[2][t] + red[3][t]);
    else if (t < 128) { int cc = t - 64; atomicAdd(&sq[cc], red[4][cc] + red[5][cc] + red[6][cc] + red[7][cc]); }
}

__global__ void stats2_kernel(const unsigned short* __restrict__ h1b,
                              float* __restrict__ sum, float* __restrict__ sq) {
    int t = threadIdx.x; int c = t & 127; int rg = t >> 7;
    float s = 0.f, q = 0.f;
    for (int row = blockIdx.x * 2 + rg; row < N_VOX; row += gridDim.x * 2) {
        float x = bf2f(h1b[(size_t)row * 128 + c]);
        s += x; q += x * x;
    }
    __shared__ float red[4][128];
    red[rg][c] = s; red[2 + rg][c] = q;
    __syncthreads();
    if (t < 128) atomicAdd(&sum[t], red[0][t] + red[1][t]);
    else { int cc = t - 128; atomicAdd(&sq[cc], red[2][cc] + red[3][cc]); }
}

// ---------------- norm1: fA = bf16(BN1(feats)), fRaw = bf16(feats) ----------------
__global__ void norm1_kernel(const float* __restrict__ feats, const float* __restrict__ ssum,
                             const float* __restrict__ ssq, const float* __restrict__ gamma,
                             const float* __restrict__ beta, unsigned short* __restrict__ fA,
                             unsigned short* __restrict__ fRaw) {
    __shared__ float sc[64], sh[64];
    int t = threadIdx.x;
    if (t < 64) {
        float mean = ssum[t] * (1.0f / N_VOX);
        float var  = ssq[t] * (1.0f / N_VOX) - mean * mean;
        float s    = gamma[t] * rsqrtf(var + EPS_BN);
        sc[t] = s; sh[t] = beta[t] - mean * s;
    }
    __syncthreads();
    const int total = N_VOX * 64 / 8;  // 8-elem chunks
    int i = blockIdx.x * 256 + t;
    if (i >= total) return;
    int cb = (i * 8) & 63;
    const float4* src = (const float4*)(feats + (size_t)i * 8);
    float4 f0 = src[0], f1 = src[1];
    float fv[8] = {f0.x, f0.y, f0.z, f0.w, f1.x, f1.y, f1.z, f1.w};
    union { uint4 q; unsigned short u[8]; } a, r;
#pragma unroll
    for (int j = 0; j < 8; j++) {
        a.u[j] = f2bf(fv[j] * sc[cb + j] + sh[cb + j]);
        r.u[j] = f2bf(fv[j]);
    }
    *(uint4*)(fA + (size_t)i * 8) = a.q;
    *(uint4*)(fRaw + (size_t)i * 8) = r.q;
}

// ---------------- norm2: h1b = bf16(BN2(h1b)) in-place ----------------
__global__ void norm2_kernel(unsigned short* __restrict__ h1b, const float* __restrict__ ssum,
                             const float* __restrict__ ssq, const float* __restrict__ gamma,
                             const float* __restrict__ beta) {
    __shared__ float sc[128], sh[128];
    int t = threadIdx.x;
    if (t < 128) {
        float mean = ssum[t] * (1.0f / N_VOX);
        float var  = ssq[t] * (1.0f / N_VOX) - mean * mean;
        float s    = gamma[t] * rsqrtf(var + EPS_BN);
        sc[t] = s; sh[t] = beta[t] - mean * s;
    }
    __syncthreads();
    const int total = N_VOX * 128 / 8;
    int i = blockIdx.x * 256 + t;
    if (i >= total) return;
    int cb = (i * 8) & 127;
    union { uint4 q; unsigned short u[8]; } v;
    v.q = *(const uint4*)(h1b + (size_t)i * 8);
#pragma unroll
    for (int j = 0; j < 8; j++) v.u[j] = f2bf(bf2f(v.u[j]) * sc[cb + j] + sh[cb + j]);
    *(uint4*)(h1b + (size_t)i * 8) = v.q;
}

// ---------------- conv1: h1[i] = sum_k fA[inv[k][i]] @ w1[k]  (64->128, bf16 out) ----------
// m97 structure: 128x128 tile, BK=64, 4 waves x (64x64 out, 4x4 acc), global_load_lds staging
__global__ __launch_bounds__(256) void conv1_kernel(
    const unsigned short* __restrict__ fA, const unsigned short* __restrict__ w1t,
    const int* __restrict__ inv, const unsigned short* __restrict__ zp,
    unsigned short* __restrict__ h1b) {
    __shared__ __align__(16) unsigned short sA[128 * 64];
    __shared__ __align__(16) unsigned short sB[128 * 64];
    const int t = threadIdx.x, lane = t & 63, w = t >> 6;
    const int v0 = blockIdx.x * 128;
    const int srow = w * 32;            // wave stages tile rows [srow, srow+32)
    const int lrow = lane >> 3;         // 8 lanes per row
    const int lcol = (lane & 7) * 8;    // halves
    const int m0 = (w & 1) * 64, n0 = (w >> 1) * 64;
    const int l16 = lane & 15, quad = lane >> 4;
    f32x4 acc[4][4] = {};

    for (int k = 0; k < 27; k++) {
#pragma unroll
        for (int q = 0; q < 4; q++) {
            int rt = srow + q * 8 + lrow;
            int g = inv[k * N_VOX + v0 + rt];
            const unsigned short* asrc = (g < N_VOX) ? (fA + (size_t)g * 64 + lcol) : (zp + lcol);
            ASYNC16(asrc, &sA[(srow + q * 8) * 64]);
            const unsigned short* bsrc = w1t + k * 8192 + rt * 64 + lcol;
            ASYNC16(bsrc, &sB[(srow + q * 8) * 64]);
        }
        __syncthreads();
#pragma unroll
        for (int ks = 0; ks < 2; ks++) {
            bf16x8 af[4], bfr[4];
#pragma unroll
            for (int mi = 0; mi < 4; mi++)
                af[mi] = *(const bf16x8*)&sA[(m0 + mi * 16 + l16) * 64 + ks * 32 + quad * 8];
#pragma unroll
            for (int ni = 0; ni < 4; ni++)
                bfr[ni] = *(const bf16x8*)&sB[(n0 + ni * 16 + l16) * 64 + ks * 32 + quad * 8];
#pragma unroll
            for (int mi = 0; mi < 4; mi++)
#pragma unroll
                for (int ni = 0; ni < 4; ni++)
                    acc[mi][ni] = __builtin_amdgcn_mfma_f32_16x16x32_bf16(af[mi], bfr[ni], acc[mi][ni], 0, 0, 0);
        }
        __syncthreads();
    }
#pragma unroll
    for (int mi = 0; mi < 4; mi++)
#pragma unroll
        for (int r = 0; r < 4; r++) {
            int v = v0 + m0 + mi * 16 + quad * 4 + r;
            if (v < N_VOX) {
#pragma unroll
                for (int ni = 0; ni < 4; ni++)
                    h1b[(size_t)v * 128 + n0 + ni * 16 + l16] = f2bf(acc[mi][ni][r]);
            }
        }
}

// ------- conv2 + skip: out[i] = sum_k h1n[inv[k][i]] @ w2[k] + fRaw[i] @ w_nin (fp32 out) ----
// 55 BK=64 iters: jj<54 -> (ko=jj>>1, khalf=jj&1) of conv; jj==54 -> fused 1x1 skip
__global__ __launch_bounds__(256) void conv2_kernel(
    const unsigned short* __restrict__ h1n, const unsigned short* __restrict__ fRaw,
    const unsigned short* __restrict__ w2t, const unsigned short* __restrict__ w_nint,
    const int* __restrict__ inv, const unsigned short* __restrict__ zp,
    float* __restrict__ out) {
    __shared__ __align__(16) unsigned short sA[128 * 64];
    __shared__ __align__(16) unsigned short sB[128 * 64];
    const int t = threadIdx.x, lane = t & 63, w = t >> 6;
    const int v0 = blockIdx.x * 128;
    const int srow = w * 32;
    const int lrow = lane >> 3;
    const int lcol = (lane & 7) * 8;
    const int m0 = (w & 1) * 64, n0 = (w >> 1) * 64;
    const int l16 = lane & 15, quad = lane >> 4;
    f32x4 acc[4][4] = {};

    for (int jj = 0; jj < 55; jj++) {
        if (jj < 54) {
            const int ko = jj >> 1;
            const int kh = (jj & 1) * 64;
#pragma unroll
            for (int q = 0; q < 4; q++) {
                int rt = srow + q * 8 + lrow;
                int g = inv[ko * N_VOX + v0 + rt];
                const unsigned short* asrc = (g < N_VOX) ? (h1n + (size_t)g * 128 + kh + lcol) : (zp + lcol);
                ASYNC16(asrc, &sA[(srow + q * 8) * 64]);
                const unsigned short* bsrc = w2t + ko * 16384 + rt * 128 + kh + lcol;
                ASYNC16(bsrc, &sB[(srow + q * 8) * 64]);
            }
        } else {
#pragma unroll
            for (int q = 0; q < 4; q++) {
                int rt = srow + q * 8 + lrow;
                int v = v0 + rt;
                const unsigned short* asrc = (v < N_VOX) ? (fRaw + (size_t)v * 64 + lcol) : (zp + lcol);
                ASYNC16(asrc, &sA[(srow + q * 8) * 64]);
                const unsigned short* bsrc = w_nint + rt * 64 + lcol;
                ASYNC16(bsrc, &sB[(srow + q * 8) * 64]);
            }
        }
        __syncthreads();
#pragma unroll
        for (int ks = 0; ks < 2; ks++) {
            bf16x8 af[4], bfr[4];
#pragma unroll
            for (int mi = 0; mi < 4; mi++)
                af[mi] = *(const bf16x8*)&sA[(m0 + mi * 16 + l16) * 64 + ks * 32 + quad * 8];
#pragma unroll
            for (int ni = 0; ni < 4; ni++)
                bfr[ni] = *(const bf16x8*)&sB[(n0 + ni * 16 + l16) * 64 + ks * 32 + quad * 8];
#pragma unroll
            for (int mi = 0; mi < 4; mi++)
#pragma unroll
                for (int ni = 0; ni < 4; ni++)
                    acc[mi][ni] = __builtin_amdgcn_mfma_f32_16x16x32_bf16(af[mi], bfr[ni], acc[mi][ni], 0, 0, 0);
        }
        __syncthreads();
    }
#pragma unroll
    for (int mi = 0; mi < 4; mi++)
#pragma unroll
        for (int r = 0; r < 4; r++) {
            int v = v0 + m0 + mi * 16 + quad * 4 + r;
            if (v < N_VOX) {
#pragma unroll
                for (int ni = 0; ni < 4; ni++)
                    out[(size_t)v * 128 + n0 + ni * 16 + l16] = acc[mi][ni][r];
            }
        }
}

extern "C" void kernel_launch(void* const* d_in, const int* in_sizes, int n_in,
                              void* d_out, int out_size, void* d_ws, size_t ws_size,
                              hipStream_t stream) {
    const float* feats = (const float*)d_in[0];
    const float* w1    = (const float*)d_in[1];
    const float* w2    = (const float*)d_in[2];
    const float* w_nin = (const float*)d_in[3];
    const float* g1    = (const float*)d_in[4];
    const float* b1    = (const float*)d_in[5];
    const float* g2    = (const float*)d_in[6];
    const float* b2    = (const float*)d_in[7];
    const int* gidx = (const int*)d_in[8];
    const int* sidx = (const int*)d_in[9];
    float* out = (float*)d_out;

    // workspace layout (total ~125.3 MB, all 16B-aligned)
    char* ws = (char*)d_ws;
    int* inv               = (int*)(ws);                          // 21,600,512
    unsigned short* fA     = (unsigned short*)(ws + 21600512);    // 25,600,000
    unsigned short* fRaw   = (unsigned short*)(ws + 47200512);    // 25,600,000
    unsigned short* h1b    = (unsigned short*)(ws + 72800512);    // 51,200,000
    unsigned short* w1t    = (unsigned short*)(ws + 124000512);   // 442,368
    unsigned short* w2t    = (unsigned short*)(ws + 124442880);   // 884,736
    unsigned short* w_nint = (unsigned short*)(ws + 125327616);   // 16,384
    float* stats           = (float*)(ws + 125344000);            // 1,536
    unsigned short* zp     = (unsigned short*)(ws + 125345536);   // 256 (zero page)
    float* s1sum = stats, *s1sq = stats + 64, *s2sum = stats + 128, *s2sq = stats + 256;

    hipMemsetAsync(stats, 0, 1536 + 256, stream);  // stats + zero page
    fill_inv_kernel<<<2048, 256, 0, stream>>>(inv);
    build_inv_kernel<<<dim3(782, 27), 256, 0, stream>>>(sidx, gidx, inv);
    tr_w1_kernel<<<dim3(32, 27), 256, 0, stream>>>(w1, w1t);
    tr_w2_kernel<<<dim3(64, 27), 256, 0, stream>>>(w2, w2t);
    tr_wn_kernel<<<32, 256, 0, stream>>>(w_nin, w_nint);
    stats1_kernel<<<512, 256, 0, stream>>>(feats, s1sum, s1sq);
    norm1_kernel<<<6250, 256, 0, stream>>>(feats, s1sum, s1sq, g1, b1, fA, fRaw);
    conv1_kernel<<<1563, 256, 0, stream>>>(fA, w1t, inv, zp, h1b);
    stats2_kernel<<<512, 256, 0, stream>>>(h1b, s2sum, s2sq);
    norm2_kernel<<<12500, 256, 0, stream>>>(h1b, s2sum, s2sq, g2, b2);
    conv2_kernel<<<1563, 256, 0, stream>>>(h1b, fRaw, w2t, w_nint, inv, zp, out);
}